// Round 1
// baseline (711.966 us; speedup 1.0000x reference)
//
#include <hip/hip_runtime.h>
#include <cstdint>
#include <cstddef>

// GCN_EW: 2-layer GCN with exp edge weights, gcn_norm w/ self-loops,
// training-mode BN, final 64->1 projection.
// B=2, N=50000, E=800000, IN=128, HID=64.
//
// Pipeline:
//  memset(ctrl)  -> k_deg (atomic deg) -> k_dinv -> k_fill (padded buckets)
//  k_gemm<128,false> : bufA = x @ W1
//  k_agg  : bufB = raw aggregate (self-loop + edges), no bias/relu
//  k_ofl  : exact fallback for bucket overflow (expected empty)
//  k_stats: BN1 sums over relu(bufB + b1)
//  k_scale: per-channel scale/shift
//  k_gemm<64,true> : bufA = bn1(relu(bufB+b1)) @ W2   (BN fused into staging)
//  k_agg / k_ofl / k_stats / k_scale  (layer 2)
//  k_out  : out = bn2(relu(bufB+b2)) . Wc + bc   (wave-reduce over 64 ch)

#define CAP  64
#define OCAP 65536
#define BN_EPS 1e-5f

__global__ void k_deg(const float* __restrict__ ew, const int* __restrict__ ei,
                      float* __restrict__ deg, int E) {
  int e = blockIdx.x * blockDim.x + threadIdx.x;
  if (e < E) atomicAdd(&deg[ei[(size_t)E + e]], expf(ew[e]));
}

__global__ void k_dinv(float* __restrict__ deg, int N) {
  int i = blockIdx.x * blockDim.x + threadIdx.x;
  if (i < N) deg[i] = rsqrtf(deg[i] + 1.0f);  // self-loop weight 1 included
}

__global__ void k_fill(const float* __restrict__ ew, const int* __restrict__ ei,
                       const float* __restrict__ dinv, int* __restrict__ cnt,
                       int* __restrict__ row_pad, float* __restrict__ norm_pad,
                       int* __restrict__ ofl_cnt, int* __restrict__ ofl_list, int E) {
  int e = blockIdx.x * blockDim.x + threadIdx.x;
  if (e >= E) return;
  int r = ei[e];
  int c = ei[(size_t)E + e];
  float nrm = dinv[r] * expf(ew[e]) * dinv[c];
  int pos = atomicAdd(&cnt[c], 1);
  if (pos < CAP) {
    row_pad[(size_t)c * CAP + pos] = r;
    norm_pad[(size_t)c * CAP + pos] = nrm;
  } else {
    int o = atomicAdd(ofl_cnt, 1);
    if (o < OCAP) ofl_list[o] = e;
  }
}

// out[nrows,64] = transform(in)[nrows,CIN] @ W[CIN,64]
// TR: v -> relu(v + bias[k]) * scsh[k] + scsh[64+k]   (fused BN of previous layer)
template<int CIN, bool TR>
__global__ void k_gemm(const float* __restrict__ in, const float* __restrict__ W,
                       float* __restrict__ out, int nrows,
                       const float* __restrict__ bias, const float* __restrict__ scsh) {
  __shared__ float lds[4 * CIN];
  int tid = threadIdx.x;
  int row0 = blockIdx.x * 4;
  for (int idx = tid; idx < 4 * CIN; idx += 256) {
    int r = idx / CIN, k = idx - r * CIN;
    int gr = row0 + r;
    float v = (gr < nrows) ? in[(size_t)gr * CIN + k] : 0.0f;
    if (TR) v = fmaxf(v + bias[k], 0.0f) * scsh[k] + scsh[64 + k];
    lds[idx] = v;
  }
  __syncthreads();
  int rl = tid >> 6, c = tid & 63;
  float acc = 0.0f;
#pragma unroll 8
  for (int k = 0; k < CIN; ++k)
    acc = fmaf(lds[rl * CIN + k], W[k * 64 + c], acc);
  int gr = row0 + rl;
  if (gr < nrows) out[(size_t)gr * 64 + c] = acc;
}

// One wave per (b, node): raw[b*N+node, lane] = h[b,node,lane]*dinv^2
//   + sum_k norm_pad[node,k] * h[b, row_pad[node,k], lane]
__global__ void k_agg(const float* __restrict__ h, const int* __restrict__ row_pad,
                      const float* __restrict__ norm_pad, const int* __restrict__ cnt,
                      const float* __restrict__ dinv, float* __restrict__ raw, int N) {
  int wid = blockIdx.x * 4 + (threadIdx.x >> 6);
  if (wid >= 2 * N) return;
  int lane = threadIdx.x & 63;
  int b = wid >= N ? 1 : 0;
  int node = wid - b * N;
  const float* hb = h + (size_t)b * N * 64;
  float d = dinv[node];
  float acc = hb[(size_t)node * 64 + lane] * d * d;
  int n = cnt[node];
  n = n > CAP ? CAP : n;
  size_t base = (size_t)node * CAP;
  for (int k = 0; k < n; ++k) {
    int r = row_pad[base + k];
    float w = norm_pad[base + k];
    acc = fmaf(w, hb[(size_t)r * 64 + lane], acc);
  }
  raw[(size_t)wid * 64 + lane] = acc;
}

// Exact fallback: add overflow-edge contributions (expected 0 iterations).
__global__ void k_ofl(const float* __restrict__ ew, const int* __restrict__ ei,
                      const float* __restrict__ dinv, const int* __restrict__ ofl_cnt,
                      const int* __restrict__ ofl_list,
                      const float* __restrict__ h, float* __restrict__ raw,
                      int N, int E) {
  int tot = *ofl_cnt;
  if (tot > OCAP) tot = OCAP;
  for (int i = blockIdx.x * blockDim.x + threadIdx.x; i < tot;
       i += gridDim.x * blockDim.x) {
    int e = ofl_list[i];
    int r = ei[e];
    int c = ei[(size_t)E + e];
    float nrm = dinv[r] * expf(ew[e]) * dinv[c];
    for (int b = 0; b < 2; ++b)
      for (int j = 0; j < 64; ++j)
        atomicAdd(&raw[((size_t)b * N + c) * 64 + j],
                  nrm * h[((size_t)b * N + r) * 64 + j]);
  }
}

// BN sums over y = relu(raw + bias): stats[c] += sum y, stats[64+c] += sum y^2
__global__ void k_stats(const float* __restrict__ raw, const float* __restrict__ bias,
                        float* __restrict__ stats, int rows) {
  __shared__ float S[256], Q[256];
  int tid = threadIdx.x;
  int c = tid & 63, rg = tid >> 6;
  float s = 0.0f, q = 0.0f;
  for (int r = blockIdx.x * 4 + rg; r < rows; r += gridDim.x * 4) {
    float y = fmaxf(raw[(size_t)r * 64 + c] + bias[c], 0.0f);
    s += y;
    q += y * y;
  }
  S[tid] = s; Q[tid] = q;
  __syncthreads();
  if (tid < 64) {
    float ts = S[tid] + S[tid + 64] + S[tid + 128] + S[tid + 192];
    float tq = Q[tid] + Q[tid + 64] + Q[tid + 128] + Q[tid + 192];
    atomicAdd(&stats[tid], ts);
    atomicAdd(&stats[64 + tid], tq);
  }
}

__global__ void k_scale(const float* __restrict__ stats, const float* __restrict__ g,
                        const float* __restrict__ be, float* __restrict__ scsh,
                        float invCnt) {
  int c = threadIdx.x;
  if (c >= 64) return;
  float m = stats[c] * invCnt;
  float v = stats[64 + c] * invCnt - m * m;
  v = v < 0.0f ? 0.0f : v;
  float inv = rsqrtf(v + BN_EPS);
  float sc = g[c] * inv;
  scsh[c] = sc;
  scsh[64 + c] = be[c] - m * sc;
}

// out[row] = sum_c (relu(raw+b2)*sc2+sh2)[c] * Wc[c] + bc
__global__ void k_out(const float* __restrict__ raw, const float* __restrict__ bias,
                      const float* __restrict__ scsh, const float* __restrict__ Wc,
                      const float* __restrict__ bc, float* __restrict__ out, int rows) {
  int row = blockIdx.x * 4 + (threadIdx.x >> 6);
  int c = threadIdx.x & 63;
  if (row >= rows) return;
  float v = fmaxf(raw[(size_t)row * 64 + c] + bias[c], 0.0f) * scsh[c] + scsh[64 + c];
  float p = v * Wc[c];
#pragma unroll
  for (int off = 32; off > 0; off >>= 1) p += __shfl_xor(p, off, 64);
  if (c == 0) out[row] = p + bc[0];
}

extern "C" void kernel_launch(void* const* d_in, const int* in_sizes, int n_in,
                              void* d_out, int out_size, void* d_ws, size_t ws_size,
                              hipStream_t stream) {
  const float* x   = (const float*)d_in[0];
  const float* ew  = (const float*)d_in[1];
  const float* W1  = (const float*)d_in[2];
  const float* b1  = (const float*)d_in[3];
  const float* W2  = (const float*)d_in[4];
  const float* b2  = (const float*)d_in[5];
  const float* g1  = (const float*)d_in[6];
  const float* be1 = (const float*)d_in[7];
  const float* g2  = (const float*)d_in[8];
  const float* be2 = (const float*)d_in[9];
  const float* Wc  = (const float*)d_in[10];
  const float* bc  = (const float*)d_in[11];
  const int*   ei  = (const int*)d_in[12];

  const int E  = in_sizes[1];
  const int BN = in_sizes[0] / 128;  // B*N = 100000
  const int N  = BN / 2;

  char* w = (char*)d_ws;
  size_t off = 0;
  float* dinv   = (float*)(w + off); off += (size_t)N * 4;
  int*   cnt    = (int*)  (w + off); off += (size_t)N * 4;
  float* stats1 = (float*)(w + off); off += 512;
  float* stats2 = (float*)(w + off); off += 512;
  int*   oflc   = (int*)  (w + off); off += 16;
  size_t zbytes = off;               // everything above must start at 0
  float* scsh1  = (float*)(w + off); off += 512;
  float* scsh2  = (float*)(w + off); off += 512;
  int*   ofll   = (int*)  (w + off); off += (size_t)OCAP * 4;
  off = (off + 255) & ~(size_t)255;
  int*   row_pad  = (int*)  (w + off); off += (size_t)N * CAP * 4;
  float* norm_pad = (float*)(w + off); off += (size_t)N * CAP * 4;
  float* bufA     = (float*)(w + off); off += (size_t)BN * 64 * 4;
  float* bufB     = (float*)(w + off); off += (size_t)BN * 64 * 4;

  float* out = (float*)d_out;

  hipMemsetAsync(w, 0, zbytes, stream);

  dim3 blk(256);
  int gE  = (E + 255) / 256;
  int gN  = (N + 255) / 256;
  int gR  = (BN + 3) / 4;       // 4 rows (waves) per block
  int gA  = (2 * N + 3) / 4;    // == gR

  k_deg<<<gE, blk, 0, stream>>>(ew, ei, dinv, E);
  k_dinv<<<gN, blk, 0, stream>>>(dinv, N);
  k_fill<<<gE, blk, 0, stream>>>(ew, ei, dinv, cnt, row_pad, norm_pad, oflc, ofll, E);

  // ---- layer 1 ----
  k_gemm<128, false><<<gR, blk, 0, stream>>>(x, W1, bufA, BN, nullptr, nullptr);
  k_agg<<<gA, blk, 0, stream>>>(bufA, row_pad, norm_pad, cnt, dinv, bufB, N);
  k_ofl<<<16, blk, 0, stream>>>(ew, ei, dinv, oflc, ofll, bufA, bufB, N, E);
  k_stats<<<400, blk, 0, stream>>>(bufB, b1, stats1, BN);
  k_scale<<<1, 64, 0, stream>>>(stats1, g1, be1, scsh1, 1.0f / (float)BN);

  // ---- layer 2 ----
  k_gemm<64, true><<<gR, blk, 0, stream>>>(bufB, W2, bufA, BN, b1, scsh1);
  k_agg<<<gA, blk, 0, stream>>>(bufA, row_pad, norm_pad, cnt, dinv, bufB, N);
  k_ofl<<<16, blk, 0, stream>>>(ew, ei, dinv, oflc, ofll, bufA, bufB, N, E);
  k_stats<<<400, blk, 0, stream>>>(bufB, b2, stats2, BN);
  k_scale<<<1, 64, 0, stream>>>(stats2, g2, be2, scsh2, 1.0f / (float)BN);

  // ---- head ----
  k_out<<<gR, blk, 0, stream>>>(bufB, b2, scsh2, Wc, bc, out, BN);
}

// Round 2
// 535.622 us; speedup vs baseline: 1.3292x; 1.3292x over previous
//
#include <hip/hip_runtime.h>
#include <cstdint>
#include <cstddef>

// GCN_EW: 2-layer GCN with exp edge weights, gcn_norm w/ self-loops,
// training-mode BN, final 64->1 projection.
// B=2, N=50000, E=800000, IN=128, HID=64.
//
// R2: batch-fused h layout [node][b][64] (512 B/node) so one wave/node
// gathers BOTH batches per edge with float2 lanes; packed (row,norm) int2
// index pairs; 4x-unrolled gather loop for memory-level parallelism.
// Row order everywhere downstream is r = node*2 + b (BN stats are
// row-order invariant; only layer-1 input map and final output map care).

#define CAP  64
#define OCAP 65536
#define BN_EPS 1e-5f

__global__ void k_deg(const float* __restrict__ ew, const int* __restrict__ ei,
                      float* __restrict__ deg, int E) {
  int e = blockIdx.x * blockDim.x + threadIdx.x;
  if (e < E) atomicAdd(&deg[ei[(size_t)E + e]], expf(ew[e]));
}

__global__ void k_dinv(float* __restrict__ deg, int N) {
  int i = blockIdx.x * blockDim.x + threadIdx.x;
  if (i < N) deg[i] = rsqrtf(deg[i] + 1.0f);  // self-loop weight 1 included
}

// pairs[c*CAP+pos] = (src_row, bits(norm)); overflow -> exact fallback list
__global__ void k_fill(const float* __restrict__ ew, const int* __restrict__ ei,
                       const float* __restrict__ dinv, int* __restrict__ cnt,
                       int2* __restrict__ pairs,
                       int* __restrict__ ofl_cnt, int* __restrict__ ofl_list, int E) {
  int e = blockIdx.x * blockDim.x + threadIdx.x;
  if (e >= E) return;
  int r = ei[e];
  int c = ei[(size_t)E + e];
  float nrm = dinv[r] * expf(ew[e]) * dinv[c];
  int pos = atomicAdd(&cnt[c], 1);
  if (pos < CAP) {
    pairs[(size_t)c * CAP + pos] = make_int2(r, __float_as_int(nrm));
  } else {
    int o = atomicAdd(ofl_cnt, 1);
    if (o < OCAP) ofl_list[o] = e;
  }
}

// out[orow,64] = transform(in)[gr,CIN] @ W[CIN,64]
// PERM: input rows are [b][node] order (gr=b*N+node), output row = node*2+b.
// TR: v -> relu(v + bias[k]) * scsh[k] + scsh[64+k]  (fused BN of prev layer)
template<int CIN, bool TR, bool PERM>
__global__ void k_gemm(const float* __restrict__ in, const float* __restrict__ W,
                       float* __restrict__ out, int nrows, int N,
                       const float* __restrict__ bias, const float* __restrict__ scsh) {
  __shared__ float lds[4 * CIN];
  int tid = threadIdx.x;
  int row0 = blockIdx.x * 4;
  for (int idx = tid; idx < 4 * CIN; idx += 256) {
    int r = idx / CIN, k = idx - r * CIN;
    int gr = row0 + r;
    float v = (gr < nrows) ? in[(size_t)gr * CIN + k] : 0.0f;
    if (TR) v = fmaxf(v + bias[k], 0.0f) * scsh[k] + scsh[64 + k];
    lds[idx] = v;
  }
  __syncthreads();
  int rl = tid >> 6, c = tid & 63;
  float acc = 0.0f;
#pragma unroll 8
  for (int k = 0; k < CIN; ++k)
    acc = fmaf(lds[rl * CIN + k], W[k * 64 + c], acc);
  int gr = row0 + rl;
  if (gr < nrows) {
    int orow = PERM ? ((gr < N) ? gr * 2 : (gr - N) * 2 + 1) : gr;
    out[(size_t)orow * 64 + c] = acc;
  }
}

// One wave per node; lane i holds float2 = channels (2i,2i+1) of the 128
// batch-fused channels. raw[node][:] = self*dinv^2 + sum_k norm_k*h[row_k][:]
__global__ void k_agg(const float* __restrict__ h, const int2* __restrict__ pairs,
                      const int* __restrict__ cnt, const float* __restrict__ dinv,
                      float* __restrict__ raw, int N) {
  int node = blockIdx.x * 4 + (threadIdx.x >> 6);
  if (node >= N) return;
  int lane = threadIdx.x & 63;
  const float2* hv = (const float2*)h;      // 64 float2 per node-row
  float d = dinv[node];
  d = d * d;
  float2 self = hv[(size_t)node * 64 + lane];
  float2 acc = make_float2(self.x * d, self.y * d);
  int n = cnt[node];
  n = n > CAP ? CAP : n;
  const int2* pp = pairs + (size_t)node * CAP;
  int k = 0;
  for (; k + 4 <= n; k += 4) {
    int2 p0 = pp[k], p1 = pp[k + 1], p2 = pp[k + 2], p3 = pp[k + 3];
    float2 v0 = hv[(size_t)p0.x * 64 + lane];
    float2 v1 = hv[(size_t)p1.x * 64 + lane];
    float2 v2 = hv[(size_t)p2.x * 64 + lane];
    float2 v3 = hv[(size_t)p3.x * 64 + lane];
    float w0 = __int_as_float(p0.y), w1 = __int_as_float(p1.y);
    float w2 = __int_as_float(p2.y), w3 = __int_as_float(p3.y);
    acc.x = fmaf(w0, v0.x, acc.x); acc.y = fmaf(w0, v0.y, acc.y);
    acc.x = fmaf(w1, v1.x, acc.x); acc.y = fmaf(w1, v1.y, acc.y);
    acc.x = fmaf(w2, v2.x, acc.x); acc.y = fmaf(w2, v2.y, acc.y);
    acc.x = fmaf(w3, v3.x, acc.x); acc.y = fmaf(w3, v3.y, acc.y);
  }
  for (; k < n; ++k) {
    int2 p = pp[k];
    float2 v = hv[(size_t)p.x * 64 + lane];
    float w = __int_as_float(p.y);
    acc.x = fmaf(w, v.x, acc.x); acc.y = fmaf(w, v.y, acc.y);
  }
  ((float2*)raw)[(size_t)node * 64 + lane] = acc;
}

// Exact fallback for bucket overflow (expected empty). Layout [node][b][64].
__global__ void k_ofl(const float* __restrict__ ew, const int* __restrict__ ei,
                      const float* __restrict__ dinv, const int* __restrict__ ofl_cnt,
                      const int* __restrict__ ofl_list,
                      const float* __restrict__ h, float* __restrict__ raw,
                      int N, int E) {
  int tot = *ofl_cnt;
  if (tot > OCAP) tot = OCAP;
  for (int i = blockIdx.x * blockDim.x + threadIdx.x; i < tot;
       i += gridDim.x * blockDim.x) {
    int e = ofl_list[i];
    int r = ei[e];
    int c = ei[(size_t)E + e];
    float nrm = dinv[r] * expf(ew[e]) * dinv[c];
    for (int j = 0; j < 128; ++j)
      atomicAdd(&raw[(size_t)c * 128 + j], nrm * h[(size_t)r * 128 + j]);
  }
}

// BN sums over y = relu(raw + bias): stats[c] += sum y, stats[64+c] += sum y^2
__global__ void k_stats(const float* __restrict__ raw, const float* __restrict__ bias,
                        float* __restrict__ stats, int rows) {
  __shared__ float S[256], Q[256];
  int tid = threadIdx.x;
  int c = tid & 63, rg = tid >> 6;
  float s = 0.0f, q = 0.0f;
  for (int r = blockIdx.x * 4 + rg; r < rows; r += gridDim.x * 4) {
    float y = fmaxf(raw[(size_t)r * 64 + c] + bias[c], 0.0f);
    s += y;
    q += y * y;
  }
  S[tid] = s; Q[tid] = q;
  __syncthreads();
  if (tid < 64) {
    float ts = S[tid] + S[tid + 64] + S[tid + 128] + S[tid + 192];
    float tq = Q[tid] + Q[tid + 64] + Q[tid + 128] + Q[tid + 192];
    atomicAdd(&stats[tid], ts);
    atomicAdd(&stats[64 + tid], tq);
  }
}

__global__ void k_scale(const float* __restrict__ stats, const float* __restrict__ g,
                        const float* __restrict__ be, float* __restrict__ scsh,
                        float invCnt) {
  int c = threadIdx.x;
  if (c >= 64) return;
  float m = stats[c] * invCnt;
  float v = stats[64 + c] * invCnt - m * m;
  v = v < 0.0f ? 0.0f : v;
  float inv = rsqrtf(v + BN_EPS);
  float sc = g[c] * inv;
  scsh[c] = sc;
  scsh[64 + c] = be[c] - m * sc;
}

// rows are (node,b): r -> out[b*N + node]
__global__ void k_out(const float* __restrict__ raw, const float* __restrict__ bias,
                      const float* __restrict__ scsh, const float* __restrict__ Wc,
                      const float* __restrict__ bc, float* __restrict__ out,
                      int rows, int N) {
  int row = blockIdx.x * 4 + (threadIdx.x >> 6);
  int c = threadIdx.x & 63;
  if (row >= rows) return;
  float v = fmaxf(raw[(size_t)row * 64 + c] + bias[c], 0.0f) * scsh[c] + scsh[64 + c];
  float p = v * Wc[c];
#pragma unroll
  for (int off = 32; off > 0; off >>= 1) p += __shfl_xor(p, off, 64);
  if (c == 0) {
    int node = row >> 1, b = row & 1;
    out[(size_t)b * N + node] = p + bc[0];
  }
}

extern "C" void kernel_launch(void* const* d_in, const int* in_sizes, int n_in,
                              void* d_out, int out_size, void* d_ws, size_t ws_size,
                              hipStream_t stream) {
  const float* x   = (const float*)d_in[0];
  const float* ew  = (const float*)d_in[1];
  const float* W1  = (const float*)d_in[2];
  const float* b1  = (const float*)d_in[3];
  const float* W2  = (const float*)d_in[4];
  const float* b2  = (const float*)d_in[5];
  const float* g1  = (const float*)d_in[6];
  const float* be1 = (const float*)d_in[7];
  const float* g2  = (const float*)d_in[8];
  const float* be2 = (const float*)d_in[9];
  const float* Wc  = (const float*)d_in[10];
  const float* bc  = (const float*)d_in[11];
  const int*   ei  = (const int*)d_in[12];

  const int E  = in_sizes[1];
  const int BN = in_sizes[0] / 128;  // B*N = 100000
  const int N  = BN / 2;

  char* w = (char*)d_ws;
  size_t off = 0;
  float* dinv   = (float*)(w + off); off += (size_t)N * 4;
  int*   cnt    = (int*)  (w + off); off += (size_t)N * 4;
  float* stats1 = (float*)(w + off); off += 512;
  float* stats2 = (float*)(w + off); off += 512;
  int*   oflc   = (int*)  (w + off); off += 16;
  size_t zbytes = off;               // everything above must start at 0
  float* scsh1  = (float*)(w + off); off += 512;
  float* scsh2  = (float*)(w + off); off += 512;
  int*   ofll   = (int*)  (w + off); off += (size_t)OCAP * 4;
  off = (off + 255) & ~(size_t)255;
  int2*  pairs  = (int2*) (w + off); off += (size_t)N * CAP * 8;
  float* bufA   = (float*)(w + off); off += (size_t)BN * 64 * 4;
  float* bufB   = (float*)(w + off); off += (size_t)BN * 64 * 4;

  float* out = (float*)d_out;

  hipMemsetAsync(w, 0, zbytes, stream);

  dim3 blk(256);
  int gE  = (E + 255) / 256;
  int gN  = (N + 255) / 256;
  int gR  = (BN + 3) / 4;       // 4 rows (waves) per block
  int gA  = (N + 3) / 4;        // 1 wave per node (both batches fused)

  k_deg<<<gE, blk, 0, stream>>>(ew, ei, dinv, E);
  k_dinv<<<gN, blk, 0, stream>>>(dinv, N);
  k_fill<<<gE, blk, 0, stream>>>(ew, ei, dinv, cnt, pairs, oflc, ofll, E);

  // ---- layer 1 ----  bufA = x @ W1  (rows -> node*2+b order)
  k_gemm<128, false, true><<<gR, blk, 0, stream>>>(x, W1, bufA, BN, N, nullptr, nullptr);
  k_agg<<<gA, blk, 0, stream>>>(bufA, pairs, cnt, dinv, bufB, N);
  k_ofl<<<16, blk, 0, stream>>>(ew, ei, dinv, oflc, ofll, bufA, bufB, N, E);
  k_stats<<<400, blk, 0, stream>>>(bufB, b1, stats1, BN);
  k_scale<<<1, 64, 0, stream>>>(stats1, g1, be1, scsh1, 1.0f / (float)BN);

  // ---- layer 2 ----  bufA = bn1(relu(bufB+b1)) @ W2  (row order preserved)
  k_gemm<64, true, false><<<gR, blk, 0, stream>>>(bufB, W2, bufA, BN, N, b1, scsh1);
  k_agg<<<gA, blk, 0, stream>>>(bufA, pairs, cnt, dinv, bufB, N);
  k_ofl<<<16, blk, 0, stream>>>(ew, ei, dinv, oflc, ofll, bufA, bufB, N, E);
  k_stats<<<400, blk, 0, stream>>>(bufB, b2, stats2, BN);
  k_scale<<<1, 64, 0, stream>>>(stats2, g2, be2, scsh2, 1.0f / (float)BN);

  // ---- head ----
  k_out<<<gR, blk, 0, stream>>>(bufB, b2, scsh2, Wc, bc, out, BN, N);
}